// Round 7
// baseline (232.632 us; speedup 1.0000x reference)
//
#include <hip/hip_runtime.h>

#define HASH_T    2097152u
#define HASH_MASK 2097151u
#define PRIME1 2654435761u
#define PRIME2 805459861u

typedef __attribute__((ext_vector_type(8))) short bf16x8;
typedef __attribute__((ext_vector_type(4))) float f32x4;
typedef __attribute__((ext_vector_type(4))) unsigned short us4;

#define LDS_STRIDE 328   // cols 0..63 feat/act0, 64..319 x->h2->h3, pad 8

__device__ __forceinline__ unsigned short bf16_hi(float x){
    unsigned u = __float_as_uint(x);
    return (unsigned short)((u + 0x7FFFu + ((u >> 16) & 1u)) >> 16);
}
__device__ __forceinline__ float bf16f(unsigned short h){
    return __uint_as_float((unsigned)h << 16);
}
__device__ __forceinline__ void split2(float x, unsigned short& h, unsigned short& l){
    h = bf16_hi(x);
    l = bf16_hi(x - bf16f(h));
}

// ---------------- Kernel 0: pack weights into MFMA fragment order (bf16 hi/lo)
__global__ __launch_bounds__(256) void pack_weights_kernel(
    const float* __restrict__ Wd0, const float* __restrict__ Wd1,
    const float* __restrict__ Wv0, const float* __restrict__ Wv1,
    unsigned short* __restrict__ pk)
{
    int tid = blockIdx.x * 256 + threadIdx.x;
    if (tid >= 424 * 512) return;
    int pair = tid >> 9;
    int li   = tid & 511;
    int lane = li >> 3, j = li & 7;
    int kq = ((lane >> 4) << 3) + j;
    int cl = lane & 15;
    float w;
    if (pair < 8) {                       // Wd0 [40,64], K padded to 64
        int idx = pair; int kt = idx >> 2, ct = idx & 3;
        int k = kt * 32 + kq, c = ct * 16 + cl;
        w = (k < 40) ? Wd0[k * 64 + c] : 0.0f;
    } else if (pair < 40) {               // Wd1 [64,256]
        int idx = pair - 8; int kt = idx >> 4, ct = idx & 15;
        int k = kt * 32 + kq, c = ct * 16 + cl;
        w = Wd1[k * 256 + c];
    } else if (pair < 168) {              // Wv0 rows 0..255 (x part)
        int idx = pair - 40; int kt = idx >> 4, ct = idx & 15;
        int k = kt * 32 + kq, c = ct * 16 + cl;
        w = Wv0[k * 256 + c];
    } else {                              // Wv1: packed k 0..255 = ref rows 256..511 (x)
        int idx = pair - 168;             //      packed k 256..511 = ref rows 0..255 (h2)
        int kt = idx >> 4, ct = idx & 15;
        int k = kt * 32 + kq, c = ct * 16 + cl;
        int refr = (k < 256) ? (k + 256) : (k - 256);
        w = Wv1[refr * 256 + c];
    }
    unsigned short h, l; split2(w, h, l);
    pk[(size_t)pair * 1024 + li]       = h;
    pk[(size_t)pair * 1024 + 512 + li] = l;
}

// ---------------- Kernel 1: hash-grid encode (R1 structure, max occupancy)
__global__ __launch_bounds__(256) void hash_encode_kernel(
    const float* __restrict__ means, const float* __restrict__ stds,
    const float* __restrict__ emb, float* __restrict__ feat, int NS)
{
    int gid = blockIdx.x * 256 + threadIdx.x;
    if (gid >= NS * 10) return;
    int l = gid / NS;
    int s = gid - l * NS;
    float r = (float)(16 << l);
    const float* __restrict__ embL = emb + (size_t)l * (size_t)HASH_T * 4u;

    float a0 = 0.f, a1 = 0.f, a2 = 0.f, a3 = 0.f;
    #pragma unroll
    for (int n = 0; n < 6; ++n) {
        const float* mp = means + ((size_t)s * 6 + n) * 3;
        float sd = stds[(size_t)s * 6 + n];
        float px = (mp[0] + 1.0f) * 0.5f * r - 0.5f;
        float py = (mp[1] + 1.0f) * 0.5f * r - 0.5f;
        float pz = (mp[2] + 1.0f) * 0.5f * r - 0.5f;
        float fx = floorf(px), fy = floorf(py), fz = floorf(pz);
        float rx = px - fx, ry = py - fy, rz = pz - fz;
        int ix = (int)fx, iy = (int)fy, iz = (int)fz;
        unsigned hx[2] = { (unsigned)ix,          (unsigned)(ix + 1) };
        unsigned hy[2] = { (unsigned)iy * PRIME1, (unsigned)(iy + 1) * PRIME1 };
        unsigned hz[2] = { (unsigned)iz * PRIME2, (unsigned)(iz + 1) * PRIME2 };
        float wx[2] = { 1.0f - rx, rx };
        float wy[2] = { 1.0f - ry, ry };
        float wz[2] = { 1.0f - rz, rz };
        float t8 = 8.0f * (sd * sd) * (r * r);
        float wl = erff(1.0f / fmaxf(sqrtf(t8), 1e-10f));
        float v0 = 0.f, v1 = 0.f, v2 = 0.f, v3 = 0.f;
        #pragma unroll
        for (int c = 0; c < 8; ++c) {
            int bx = (c >> 2) & 1, by = (c >> 1) & 1, bz = c & 1;
            unsigned idx = (hx[bx] ^ hy[by] ^ hz[bz]) & HASH_MASK;
            const float4 e = *reinterpret_cast<const float4*>(embL + (size_t)idx * 4u);
            float w = wx[bx] * wy[by] * wz[bz];
            v0 += w * e.x; v1 += w * e.y; v2 += w * e.z; v3 += w * e.w;
        }
        a0 += wl * v0; a1 += wl * v1; a2 += wl * v2; a3 += wl * v3;
    }
    const float inv6 = 1.0f / 6.0f;
    float4 o; o.x = a0 * inv6; o.y = a1 * inv6; o.z = a2 * inv6; o.w = a3 * inv6;
    *reinterpret_cast<float4*>(feat + (size_t)s * 40 + l * 4) = o;
}

// ---------------- MLP helpers: ROLLED K-loops (I$-small) ---------------------
template<int KT, int NC>
__device__ __forceinline__ void gemm32_rolled(
    const unsigned short* __restrict__ pkBase, int NCT, int ct0, int kOff,
    const unsigned short (*Ahi)[LDS_STRIDE], const unsigned short (*Alo)[LDS_STRIDE],
    int lane, f32x4 acc[NC][2])
{
    const int r = lane & 15;
    const int kg = (lane >> 4) * 8;
    #pragma unroll 1
    for (int kt = 0; kt < KT; ++kt) {
        const int ke = kOff + kt * 32 + kg;
        bf16x8 bh[2], bl[2];
        #pragma unroll
        for (int st = 0; st < 2; ++st) {
            bh[st] = *reinterpret_cast<const bf16x8*>(&Ahi[st * 16 + r][ke]);
            bl[st] = *reinterpret_cast<const bf16x8*>(&Alo[st * 16 + r][ke]);
        }
        #pragma unroll
        for (int ci = 0; ci < NC; ++ci) {
            const unsigned short* pf = pkBase + (size_t)(kt * NCT + ct0 + ci) * 1024 + (size_t)lane * 8;
            bf16x8 ah = *reinterpret_cast<const bf16x8*>(pf);
            bf16x8 al = *reinterpret_cast<const bf16x8*>(pf + 512);
            #pragma unroll
            for (int st = 0; st < 2; ++st) {
                acc[ci][st] = __builtin_amdgcn_mfma_f32_16x16x32_bf16(ah, bh[st], acc[ci][st], 0, 0, 0);
                acc[ci][st] = __builtin_amdgcn_mfma_f32_16x16x32_bf16(ah, bl[st], acc[ci][st], 0, 0, 0);
                acc[ci][st] = __builtin_amdgcn_mfma_f32_16x16x32_bf16(al, bh[st], acc[ci][st], 0, 0, 0);
            }
        }
    }
}

// dual-accumulator: two weight matrices share one B-fragment read (x-region)
__device__ __forceinline__ void gemm32_dual(
    const unsigned short* __restrict__ pA, const unsigned short* __restrict__ pB,
    int ct0, int kOff,
    const unsigned short (*Ahi)[LDS_STRIDE], const unsigned short (*Alo)[LDS_STRIDE],
    int lane, f32x4 accA[4][2], f32x4 accB[4][2])
{
    const int r = lane & 15;
    const int kg = (lane >> 4) * 8;
    #pragma unroll 1
    for (int kt = 0; kt < 8; ++kt) {
        const int ke = kOff + kt * 32 + kg;
        bf16x8 bh[2], bl[2];
        #pragma unroll
        for (int st = 0; st < 2; ++st) {
            bh[st] = *reinterpret_cast<const bf16x8*>(&Ahi[st * 16 + r][ke]);
            bl[st] = *reinterpret_cast<const bf16x8*>(&Alo[st * 16 + r][ke]);
        }
        #pragma unroll
        for (int ci = 0; ci < 4; ++ci) {
            const size_t off = (size_t)(kt * 16 + ct0 + ci) * 1024 + (size_t)lane * 8;
            const unsigned short* fA = pA + off;
            bf16x8 ahA = *reinterpret_cast<const bf16x8*>(fA);
            bf16x8 alA = *reinterpret_cast<const bf16x8*>(fA + 512);
            const unsigned short* fB = pB + off;
            bf16x8 ahB = *reinterpret_cast<const bf16x8*>(fB);
            bf16x8 alB = *reinterpret_cast<const bf16x8*>(fB + 512);
            #pragma unroll
            for (int st = 0; st < 2; ++st) {
                accA[ci][st] = __builtin_amdgcn_mfma_f32_16x16x32_bf16(ahA, bh[st], accA[ci][st], 0, 0, 0);
                accA[ci][st] = __builtin_amdgcn_mfma_f32_16x16x32_bf16(ahA, bl[st], accA[ci][st], 0, 0, 0);
                accA[ci][st] = __builtin_amdgcn_mfma_f32_16x16x32_bf16(alA, bh[st], accA[ci][st], 0, 0, 0);
                accB[ci][st] = __builtin_amdgcn_mfma_f32_16x16x32_bf16(ahB, bh[st], accB[ci][st], 0, 0, 0);
                accB[ci][st] = __builtin_amdgcn_mfma_f32_16x16x32_bf16(ahB, bl[st], accB[ci][st], 0, 0, 0);
                accB[ci][st] = __builtin_amdgcn_mfma_f32_16x16x32_bf16(alB, bh[st], accB[ci][st], 0, 0, 0);
            }
        }
    }
}

template<int NC, bool RELU>
__device__ __forceinline__ void epi32(
    f32x4 acc[NC][2], int ct0, int lane, const float* bias, int outOff,
    unsigned short (*Ahi)[LDS_STRIDE], unsigned short (*Alo)[LDS_STRIDE])
{
    const int r = lane & 15, g = lane >> 4;
    #pragma unroll
    for (int ci = 0; ci < NC; ++ci) {
        const int c0 = (ct0 + ci) * 16 + g * 4;
        const float4 bb = *reinterpret_cast<const float4*>(&bias[c0]);
        #pragma unroll
        for (int st = 0; st < 2; ++st) {
            const int s = st * 16 + r;
            float v[4] = { acc[ci][st][0] + bb.x, acc[ci][st][1] + bb.y,
                           acc[ci][st][2] + bb.z, acc[ci][st][3] + bb.w };
            us4 H, L;
            #pragma unroll
            for (int q = 0; q < 4; ++q) {
                float vv = RELU ? fmaxf(v[q], 0.0f) : v[q];
                unsigned short h, l; split2(vv, h, l);
                H[q] = h; L[q] = l;
            }
            *reinterpret_cast<us4*>(&Ahi[s][outOff + c0]) = H;
            *reinterpret_cast<us4*>(&Alo[s][outOff + c0]) = L;
        }
    }
}

// ---------------- Kernel 2: MFMA MLP, one ray (32 samples) per block ---------
__global__ __launch_bounds__(256, 3) void mlp_mfma_kernel(
    const float* __restrict__ feat, const float* __restrict__ vdirs,
    const unsigned short* __restrict__ pk,
    const float* __restrict__ bd0, const float* __restrict__ bd1,
    const float* __restrict__ Wv0, const float* __restrict__ bv0,
    const float* __restrict__ Wv1, const float* __restrict__ bv1,
    const float* __restrict__ Wr,  const float* __restrict__ br,
    float* __restrict__ outD, float* __restrict__ outRGB)
{
    __shared__ __align__(16) unsigned short sAhi[32][LDS_STRIDE];
    __shared__ __align__(16) unsigned short sAlo[32][LDS_STRIDE];
    __shared__ float sDe[32];
    __shared__ float sDv0[256];
    __shared__ float sDv1[256];

    const int t = threadIdx.x;
    const int lane = t & 63;
    const int w = t >> 6;
    const int b = blockIdx.x;          // ray index
    const int base = b * 32;

    // ---- phase 0: stage feat (cols 0..39) + zero-pad (40..63); dir encoding
    {
        int s = t >> 3, kg = t & 7;
        float v[8];
        if (kg < 5) {
            const float4 f0 = *reinterpret_cast<const float4*>(feat + (size_t)(base + s) * 40 + kg * 8);
            const float4 f1 = *reinterpret_cast<const float4*>(feat + (size_t)(base + s) * 40 + kg * 8 + 4);
            v[0]=f0.x; v[1]=f0.y; v[2]=f0.z; v[3]=f0.w;
            v[4]=f1.x; v[5]=f1.y; v[6]=f1.z; v[7]=f1.w;
        } else {
            #pragma unroll
            for (int q = 0; q < 8; ++q) v[q] = 0.0f;
        }
        us4 H0, H1, L0v, L1v;
        #pragma unroll
        for (int q = 0; q < 4; ++q) {
            unsigned short h, l;
            split2(v[q], h, l);       H0[q] = h; L0v[q] = l;
            split2(v[q + 4], h, l);   H1[q] = h; L1v[q] = l;
        }
        *reinterpret_cast<us4*>(&sAhi[s][kg * 8])     = H0;
        *reinterpret_cast<us4*>(&sAhi[s][kg * 8 + 4]) = H1;
        *reinterpret_cast<us4*>(&sAlo[s][kg * 8])     = L0v;
        *reinterpret_cast<us4*>(&sAlo[s][kg * 8 + 4]) = L1v;
    }
    if (t < 27) {
        float d0 = vdirs[b * 3 + 0], d1 = vdirs[b * 3 + 1], d2 = vdirs[b * 3 + 2];
        float val;
        if (t < 3) val = (t == 0) ? d0 : ((t == 1) ? d1 : d2);
        else {
            int u = t - 3, half = u / 12, jk = u % 12;
            int j = jk / 3, k = jk % 3;
            float dk = (k == 0) ? d0 : ((k == 1) ? d1 : d2);
            float xb = dk * (float)(1 << j);
            val = sinf(half ? (xb + 1.57079632679489662f) : xb);
        }
        sDe[t] = val;
    }
    __syncthreads();

    // ---- phase 1: per-ray dir-enc + bias tables (rank-27 correction)
    {
        int c = t;
        float a0 = bv0[c], a1 = bv1[c];
        #pragma unroll 3
        for (int k = 0; k < 27; ++k) {
            float dv = sDe[k];
            a0 += dv * Wv0[(256 + k) * 256 + c];
            a1 += dv * Wv1[(512 + k) * 256 + c];
        }
        sDv0[c] = a0; sDv1[c] = a1;
    }
    __syncthreads();

    // ---- phase 2 (L0): feat @ Wd0 -> act0 (cols 0..63), relu
    {
        f32x4 acc[1][2] = {};
        gemm32_rolled<2, 1>(pk, 4, w, 0, sAhi, sAlo, lane, acc);
        __syncthreads();                 // feat reads done before overwrite
        epi32<1, true>(acc, w, lane, bd0, 0, sAhi, sAlo);
    }
    __syncthreads();

    // ---- phase 3 (L1): act0 @ Wd1 -> x (cols 64..319); density from col 0
    {
        f32x4 acc[4][2] = {};
        gemm32_rolled<2, 4>(pk + 8192, 16, w * 4, 0, sAhi, sAlo, lane, acc);
        if (w == 0 && (lane >> 4) == 0) {
            #pragma unroll
            for (int st = 0; st < 2; ++st) {
                float x0 = acc[0][st][0] + bd1[0];
                int s = st * 16 + (lane & 15);
                float vv = x0 - 1.0f;
                outD[base + s] = fmaxf(vv, 0.0f) + log1pf(expf(-fabsf(vv)));
            }
        }
        __syncthreads();                 // act0 reads done
        epi32<4, false>(acc, w * 4, lane, bd1, 64, sAhi, sAlo);
    }
    __syncthreads();

    // ---- phase 4+5 merged: px = x @ Wv1[x-rows]; h2 = relu(x @ Wv0 + sDv0)
    f32x4 px[4][2] = {};
    {
        f32x4 acc[4][2] = {};
        gemm32_dual(pk + 172032, pk + 40960, w * 4, 64, sAhi, sAlo, lane, px, acc);
        __syncthreads();                 // all x reads done
        epi32<4, true>(acc, w * 4, lane, sDv0, 64, sAhi, sAlo);
    }
    __syncthreads();

    // ---- phase 6 (L3): px + h2 @ Wv1[h2-rows] + sDv1 -> h3 (cols 64..319)
    {
        gemm32_rolled<8, 4>(pk + 303104, 16, w * 4, 64, sAhi, sAlo, lane, px);
        __syncthreads();                 // h2 reads done before overwrite
        epi32<4, true>(px, w * 4, lane, sDv1, 64, sAhi, sAlo);
    }
    __syncthreads();

    // ---- phase 7 (L4): rgb = sigmoid(h3 @ Wr + br)*1.002 - 0.001
    {
        int s = t >> 3, j = t & 7, k0 = 64 + j * 32;
        float p0 = 0.f, p1 = 0.f, p2 = 0.f;
        #pragma unroll 1
        for (int q = 0; q < 4; ++q) {
            us4 vh[2], vl[2];
            *reinterpret_cast<uint4*>(vh) = *reinterpret_cast<const uint4*>(&sAhi[s][k0 + q * 8]);
            *reinterpret_cast<uint4*>(vl) = *reinterpret_cast<const uint4*>(&sAlo[s][k0 + q * 8]);
            #pragma unroll
            for (int e = 0; e < 8; ++e) {
                int k = j * 32 + q * 8 + e;
                float hv = bf16f(((const unsigned short*)vh)[e]) + bf16f(((const unsigned short*)vl)[e]);
                p0 += hv * Wr[k * 3 + 0];
                p1 += hv * Wr[k * 3 + 1];
                p2 += hv * Wr[k * 3 + 2];
            }
        }
        #pragma unroll
        for (int m = 1; m < 8; m <<= 1) {
            p0 += __shfl_xor(p0, m);
            p1 += __shfl_xor(p1, m);
            p2 += __shfl_xor(p2, m);
        }
        if (j < 3) {
            float a = ((j == 0) ? p0 : (j == 1) ? p1 : p2) + br[j];
            float sg = 1.0f / (1.0f + expf(-a));
            outRGB[(size_t)(base + s) * 3 + j] = sg * 1.002f - 0.001f;
        }
    }
}

extern "C" void kernel_launch(void* const* d_in, const int* in_sizes, int n_in,
                              void* d_out, int out_size, void* d_ws, size_t ws_size,
                              hipStream_t stream) {
    const float* means = (const float*)d_in[1];
    const float* stds_ = (const float*)d_in[2];
    const float* vdirs = (const float*)d_in[3];
    const float* emb   = (const float*)d_in[4];
    const float* Wd0 = (const float*)d_in[5];
    const float* bd0 = (const float*)d_in[6];
    const float* Wd1 = (const float*)d_in[7];
    const float* bd1 = (const float*)d_in[8];
    const float* Wv0 = (const float*)d_in[9];
    const float* bv0 = (const float*)d_in[10];
    const float* Wv1 = (const float*)d_in[11];
    const float* bv1 = (const float*)d_in[12];
    const float* Wr  = (const float*)d_in[13];
    const float* br  = (const float*)d_in[14];

    const int B  = in_sizes[3] / 3;   // 1024 rays
    const int NS = B * 32;            // 32768 samples

    float* feat = (float*)d_ws;                                   // NS*40 f32
    unsigned short* pk = (unsigned short*)((char*)d_ws + (size_t)NS * 40 * 4);

    hipLaunchKernelGGL(pack_weights_kernel, dim3((424 * 512 + 255) / 256), dim3(256), 0, stream,
                       Wd0, Wd1, Wv0, Wv1, pk);

    int total = NS * 10;
    hipLaunchKernelGGL(hash_encode_kernel, dim3((total + 255) / 256), dim3(256), 0, stream,
                       means, stds_, emb, feat, NS);

    float* outD   = (float*)d_out;
    float* outRGB = outD + NS;
    hipLaunchKernelGGL(mlp_mfma_kernel, dim3(B), dim3(256), 0, stream,
                       feat, vdirs, pk, bd0, bd1, Wv0, bv0, Wv1, bv1, Wr, br,
                       outD, outRGB);
}

// Round 8
// 216.421 us; speedup vs baseline: 1.0749x; 1.0749x over previous
//
#include <hip/hip_runtime.h>

#define HASH_T    2097152u
#define HASH_MASK 2097151u
#define PRIME1 2654435761u
#define PRIME2 805459861u

typedef __attribute__((ext_vector_type(8))) short bf16x8;
typedef __attribute__((ext_vector_type(4))) float f32x4;
typedef __attribute__((ext_vector_type(4))) unsigned short us4;

#define XS 264   // x/h2/h3 region row stride (cols 0..255 + pad)

__device__ __forceinline__ unsigned short bf16_hi(float x){
    unsigned u = __float_as_uint(x);
    return (unsigned short)((u + 0x7FFFu + ((u >> 16) & 1u)) >> 16);
}
__device__ __forceinline__ float bf16f(unsigned short h){
    return __uint_as_float((unsigned)h << 16);
}
__device__ __forceinline__ void split2(float x, unsigned short& h, unsigned short& l){
    h = bf16_hi(x);
    l = bf16_hi(x - bf16f(h));
}

// ---------------- Kernel 0: pack weights into MFMA fragment order (bf16 hi/lo)
__global__ __launch_bounds__(256) void pack_weights_kernel(
    const float* __restrict__ Wd0, const float* __restrict__ Wd1,
    const float* __restrict__ Wv0, const float* __restrict__ Wv1,
    unsigned short* __restrict__ pk)
{
    int tid = blockIdx.x * 256 + threadIdx.x;
    if (tid >= 424 * 512) return;
    int pair = tid >> 9;
    int li   = tid & 511;
    int lane = li >> 3, j = li & 7;
    int kq = ((lane >> 4) << 3) + j;
    int cl = lane & 15;
    float w;
    if (pair < 8) {                       // Wd0 [40,64], K padded to 64
        int idx = pair; int kt = idx >> 2, ct = idx & 3;
        int k = kt * 32 + kq, c = ct * 16 + cl;
        w = (k < 40) ? Wd0[k * 64 + c] : 0.0f;
    } else if (pair < 40) {               // Wd1 [64,256]
        int idx = pair - 8; int kt = idx >> 4, ct = idx & 15;
        int k = kt * 32 + kq, c = ct * 16 + cl;
        w = Wd1[k * 256 + c];
    } else if (pair < 168) {              // Wv0 rows 0..255 (x part)
        int idx = pair - 40; int kt = idx >> 4, ct = idx & 15;
        int k = kt * 32 + kq, c = ct * 16 + cl;
        w = Wv0[k * 256 + c];
    } else {                              // Wv1: packed k 0..255 = ref rows 256..511 (x)
        int idx = pair - 168;             //      packed k 256..511 = ref rows 0..255 (h2)
        int kt = idx >> 4, ct = idx & 15;
        int k = kt * 32 + kq, c = ct * 16 + cl;
        int refr = (k < 256) ? (k + 256) : (k - 256);
        w = Wv1[refr * 256 + c];
    }
    unsigned short h, l; split2(w, h, l);
    pk[(size_t)pair * 1024 + li]       = h;
    pk[(size_t)pair * 1024 + 512 + li] = l;
}

// ---------------- fused kernel helpers --------------------------------------
// x-region gemm: B-side hi/lo 3-term (R5 structure: unrolled + A prefetch)
template<int KT, int NC>
__device__ __forceinline__ void gemm32(
    const unsigned short* __restrict__ pkBase, int NCT, int ct0,
    const unsigned short (*Bhi)[XS], const unsigned short (*Blo)[XS],
    int lane, f32x4 acc[NC][2])
{
    const int r = lane & 15;
    const int kg = (lane >> 4) * 8;
    bf16x8 ah[NC], al[NC];
    #pragma unroll
    for (int ci = 0; ci < NC; ++ci) {
        const unsigned short* pf = pkBase + (size_t)(ct0 + ci) * 1024 + (size_t)lane * 8;
        ah[ci] = *reinterpret_cast<const bf16x8*>(pf);
        al[ci] = *reinterpret_cast<const bf16x8*>(pf + 512);
    }
    #pragma unroll
    for (int kt = 0; kt < KT; ++kt) {
        bf16x8 ahn[NC], aln[NC];
        if (kt + 1 < KT) {
            #pragma unroll
            for (int ci = 0; ci < NC; ++ci) {
                const unsigned short* pf = pkBase
                    + (size_t)((kt + 1) * NCT + ct0 + ci) * 1024 + (size_t)lane * 8;
                ahn[ci] = *reinterpret_cast<const bf16x8*>(pf);
                aln[ci] = *reinterpret_cast<const bf16x8*>(pf + 512);
            }
        }
        const int ke = kt * 32 + kg;
        bf16x8 bh[2], bl[2];
        #pragma unroll
        for (int st = 0; st < 2; ++st) {
            bh[st] = *reinterpret_cast<const bf16x8*>(&Bhi[st * 16 + r][ke]);
            bl[st] = *reinterpret_cast<const bf16x8*>(&Blo[st * 16 + r][ke]);
        }
        #pragma unroll
        for (int ci = 0; ci < NC; ++ci) {
            #pragma unroll
            for (int st = 0; st < 2; ++st) {
                acc[ci][st] = __builtin_amdgcn_mfma_f32_16x16x32_bf16(ah[ci], bh[st], acc[ci][st], 0, 0, 0);
                acc[ci][st] = __builtin_amdgcn_mfma_f32_16x16x32_bf16(ah[ci], bl[st], acc[ci][st], 0, 0, 0);
                acc[ci][st] = __builtin_amdgcn_mfma_f32_16x16x32_bf16(al[ci], bh[st], acc[ci][st], 0, 0, 0);
            }
        }
        if (kt + 1 < KT) {
            #pragma unroll
            for (int ci = 0; ci < NC; ++ci) { ah[ci] = ahn[ci]; al[ci] = aln[ci]; }
        }
    }
}

// sF-region gemm: B-side single bf16, A hi/lo 2-term
template<int KT, int NC>
__device__ __forceinline__ void gemm_sf(
    const unsigned short* __restrict__ pkBase, int NCT, int ct0,
    const unsigned short (*B)[64], int lane, f32x4 acc[NC][2])
{
    const int r = lane & 15;
    const int kg = (lane >> 4) * 8;
    bf16x8 ah[NC], al[NC];
    #pragma unroll
    for (int ci = 0; ci < NC; ++ci) {
        const unsigned short* pf = pkBase + (size_t)(ct0 + ci) * 1024 + (size_t)lane * 8;
        ah[ci] = *reinterpret_cast<const bf16x8*>(pf);
        al[ci] = *reinterpret_cast<const bf16x8*>(pf + 512);
    }
    #pragma unroll
    for (int kt = 0; kt < KT; ++kt) {
        bf16x8 ahn[NC], aln[NC];
        if (kt + 1 < KT) {
            #pragma unroll
            for (int ci = 0; ci < NC; ++ci) {
                const unsigned short* pf = pkBase
                    + (size_t)((kt + 1) * NCT + ct0 + ci) * 1024 + (size_t)lane * 8;
                ahn[ci] = *reinterpret_cast<const bf16x8*>(pf);
                aln[ci] = *reinterpret_cast<const bf16x8*>(pf + 512);
            }
        }
        const int ke = kt * 32 + kg;
        bf16x8 bh[2];
        #pragma unroll
        for (int st = 0; st < 2; ++st)
            bh[st] = *reinterpret_cast<const bf16x8*>(&B[st * 16 + r][ke]);
        #pragma unroll
        for (int ci = 0; ci < NC; ++ci) {
            #pragma unroll
            for (int st = 0; st < 2; ++st) {
                acc[ci][st] = __builtin_amdgcn_mfma_f32_16x16x32_bf16(ah[ci], bh[st], acc[ci][st], 0, 0, 0);
                acc[ci][st] = __builtin_amdgcn_mfma_f32_16x16x32_bf16(al[ci], bh[st], acc[ci][st], 0, 0, 0);
            }
        }
        if (kt + 1 < KT) {
            #pragma unroll
            for (int ci = 0; ci < NC; ++ci) { ah[ci] = ahn[ci]; al[ci] = aln[ci]; }
        }
    }
}

// epilogue -> x region (hi/lo)
template<int NC, bool RELU>
__device__ __forceinline__ void epi32(
    f32x4 acc[NC][2], int ct0, int lane, const float* bias,
    unsigned short (*Bhi)[XS], unsigned short (*Blo)[XS])
{
    const int r = lane & 15, g = lane >> 4;
    #pragma unroll
    for (int ci = 0; ci < NC; ++ci) {
        const int c0 = (ct0 + ci) * 16 + g * 4;
        const float4 bb = *reinterpret_cast<const float4*>(&bias[c0]);
        #pragma unroll
        for (int st = 0; st < 2; ++st) {
            const int s = st * 16 + r;
            float v[4] = { acc[ci][st][0] + bb.x, acc[ci][st][1] + bb.y,
                           acc[ci][st][2] + bb.z, acc[ci][st][3] + bb.w };
            us4 H, L;
            #pragma unroll
            for (int q = 0; q < 4; ++q) {
                float vv = RELU ? fmaxf(v[q], 0.0f) : v[q];
                unsigned short h, l; split2(vv, h, l);
                H[q] = h; L[q] = l;
            }
            *reinterpret_cast<us4*>(&Bhi[s][c0]) = H;
            *reinterpret_cast<us4*>(&Blo[s][c0]) = L;
        }
    }
}

// ---------------- Kernel 1: fused hash + MLP, one ray (32 samples) per block -
__global__ __launch_bounds__(256, 4) void zip_fused_kernel(
    const float* __restrict__ means, const float* __restrict__ stds,
    const float* __restrict__ vdirs, const float* __restrict__ emb,
    const unsigned short* __restrict__ pk,
    const float* __restrict__ bd0, const float* __restrict__ bd1,
    const float* __restrict__ Wv0, const float* __restrict__ bv0,
    const float* __restrict__ Wv1, const float* __restrict__ bv1,
    const float* __restrict__ Wr,  const float* __restrict__ br,
    float* __restrict__ outD, float* __restrict__ outRGB)
{
    __shared__ __align__(16) unsigned short sF[32][64];    // feat -> act0 (single bf16)
    __shared__ __align__(16) unsigned short sXhi[32][XS];  // x -> h2 -> h3 hi
    __shared__ __align__(16) unsigned short sXlo[32][XS];  // x -> h2 -> h3 lo
    __shared__ float sDe[32];
    __shared__ float sDv0[256];
    __shared__ float sDv1[256];

    const int t = threadIdx.x;
    const int lane = t & 63;
    const int w = t >> 6;
    const int b = blockIdx.x;          // ray index
    const int base = b * 32;

    // ---- phase 0: zero-pad feat cols 40..63; dir encoding
    if (t < 192) {
        int s = t / 6, j = t - s * 6;
        us4 z = {0, 0, 0, 0};
        *reinterpret_cast<us4*>(&sF[s][40 + j * 4]) = z;
    }
    if (t < 27) {
        float d0 = vdirs[b * 3 + 0], d1 = vdirs[b * 3 + 1], d2 = vdirs[b * 3 + 2];
        float val;
        if (t < 3) val = (t == 0) ? d0 : ((t == 1) ? d1 : d2);
        else {
            int u = t - 3, half = u / 12, jk = u % 12;
            int j = jk / 3, k = jk % 3;
            float dk = (k == 0) ? d0 : ((k == 1) ? d1 : d2);
            float xb = dk * (float)(1 << j);
            val = sinf(half ? (xb + 1.57079632679489662f) : xb);
        }
        sDe[t] = val;
    }
    __syncthreads();

    // ---- phase 1: hash gather; thread = (sample s = t>>3, multisample n = t&7)
    {
        const int s = t >> 3, n = t & 7;
        const bool act = (n < 6);
        float mx = 0.f, my = 0.f, mz = 0.f, sd2_8 = 0.f;
        if (act) {
            const float* mp = means + ((size_t)(base + s) * 6 + n) * 3;
            mx = mp[0]; my = mp[1]; mz = mp[2];
            float sd = stds[(size_t)(base + s) * 6 + n];
            sd2_8 = 8.0f * sd * sd;
        }
        const float inv6 = 1.0f / 6.0f;
        #pragma unroll 2
        for (int l = 0; l < 10; ++l) {
            float r = (float)(16 << l);
            float a0 = 0.f, a1 = 0.f, a2 = 0.f, a3 = 0.f;
            if (act) {
                float px = (mx + 1.0f) * 0.5f * r - 0.5f;
                float py = (my + 1.0f) * 0.5f * r - 0.5f;
                float pz = (mz + 1.0f) * 0.5f * r - 0.5f;
                float fx = floorf(px), fy = floorf(py), fz = floorf(pz);
                float rx = px - fx, ry = py - fy, rz = pz - fz;
                int ix = (int)fx, iy = (int)fy, iz = (int)fz;
                unsigned hx[2] = { (unsigned)ix,          (unsigned)(ix + 1) };
                unsigned hy[2] = { (unsigned)iy * PRIME1, (unsigned)(iy + 1) * PRIME1 };
                unsigned hz[2] = { (unsigned)iz * PRIME2, (unsigned)(iz + 1) * PRIME2 };
                float wx[2] = { 1.0f - rx, rx };
                float wy[2] = { 1.0f - ry, ry };
                float wz[2] = { 1.0f - rz, rz };
                float wl = erff(1.0f / fmaxf(sqrtf(sd2_8 * r * r), 1e-10f));
                #pragma unroll
                for (int c = 0; c < 8; ++c) {
                    int cx = (c >> 2) & 1, cy = (c >> 1) & 1, cz = c & 1;
                    unsigned idx = (hx[cx] ^ hy[cy] ^ hz[cz]) & HASH_MASK;
                    const float4 e = *reinterpret_cast<const float4*>(
                        emb + ((size_t)l * HASH_T + idx) * 4u);
                    float wgt = wx[cx] * wy[cy] * wz[cz];
                    a0 += wgt * e.x; a1 += wgt * e.y; a2 += wgt * e.z; a3 += wgt * e.w;
                }
                a0 *= wl; a1 *= wl; a2 *= wl; a3 *= wl;
            }
            // butterfly reduce over n (lane bits 0..2); inactive lanes hold 0
            #pragma unroll
            for (int m = 1; m < 8; m <<= 1) {
                a0 += __shfl_xor(a0, m);
                a1 += __shfl_xor(a1, m);
                a2 += __shfl_xor(a2, m);
                a3 += __shfl_xor(a3, m);
            }
            if (n == 0) {
                us4 H;
                H[0] = bf16_hi(a0 * inv6);
                H[1] = bf16_hi(a1 * inv6);
                H[2] = bf16_hi(a2 * inv6);
                H[3] = bf16_hi(a3 * inv6);
                *reinterpret_cast<us4*>(&sF[s][l * 4]) = H;
            }
        }
    }
    __syncthreads();

    // ---- phase 2: per-ray dir-enc + bias tables (rank-27 correction)
    {
        int c = t;
        float a0 = bv0[c], a1 = bv1[c];
        #pragma unroll 3
        for (int k = 0; k < 27; ++k) {
            float dv = sDe[k];
            a0 += dv * Wv0[(256 + k) * 256 + c];
            a1 += dv * Wv1[(512 + k) * 256 + c];
        }
        sDv0[c] = a0; sDv1[c] = a1;
    }
    __syncthreads();

    // ---- phase 3 (L0): feat @ Wd0 -> act0 (sF cols 0..63), relu
    {
        f32x4 acc[1][2] = {};
        gemm_sf<2, 1>(pk, 4, w, sF, lane, acc);
        __syncthreads();                 // feat reads done before overwrite
        const int r = lane & 15, g = lane >> 4;
        const int c0 = w * 16 + g * 4;
        const float4 bb = *reinterpret_cast<const float4*>(&bd0[c0]);
        #pragma unroll
        for (int st = 0; st < 2; ++st) {
            const int s = st * 16 + r;
            us4 H;
            H[0] = bf16_hi(fmaxf(acc[0][st][0] + bb.x, 0.0f));
            H[1] = bf16_hi(fmaxf(acc[0][st][1] + bb.y, 0.0f));
            H[2] = bf16_hi(fmaxf(acc[0][st][2] + bb.z, 0.0f));
            H[3] = bf16_hi(fmaxf(acc[0][st][3] + bb.w, 0.0f));
            *reinterpret_cast<us4*>(&sF[s][c0]) = H;
        }
    }
    __syncthreads();

    // ---- phase 4 (L1): act0 @ Wd1 -> x (sX cols 0..255); density from col 0
    {
        f32x4 acc[4][2] = {};
        gemm_sf<2, 4>(pk + 8192, 16, w * 4, sF, lane, acc);
        if (w == 0 && (lane >> 4) == 0) {
            #pragma unroll
            for (int st = 0; st < 2; ++st) {
                float x0 = acc[0][st][0] + bd1[0];
                int s = st * 16 + (lane & 15);
                float vv = x0 - 1.0f;
                outD[base + s] = fmaxf(vv, 0.0f) + log1pf(expf(-fabsf(vv)));
            }
        }
        epi32<4, false>(acc, w * 4, lane, bd1, sXhi, sXlo);
    }
    __syncthreads();

    // ---- phase 5: px = x @ Wv1[x-rows] (L3 partial, registers only)
    f32x4 px[4][2] = {};
    gemm32<8, 4>(pk + 172032, 16, w * 4, sXhi, sXlo, lane, px);
    __syncthreads();

    // ---- phase 6 (L2): x @ Wv0 + sDv0 -> h2 (overwrites x)
    {
        f32x4 acc[4][2] = {};
        gemm32<8, 4>(pk + 40960, 16, w * 4, sXhi, sXlo, lane, acc);
        __syncthreads();                 // all x reads (phase5+6) done
        epi32<4, true>(acc, w * 4, lane, sDv0, sXhi, sXlo);
    }
    __syncthreads();

    // ---- phase 7 (L3): px + h2 @ Wv1[h2-rows] + sDv1 -> h3
    {
        gemm32<8, 4>(pk + 303104, 16, w * 4, sXhi, sXlo, lane, px);
        __syncthreads();                 // h2 reads done before overwrite
        epi32<4, true>(px, w * 4, lane, sDv1, sXhi, sXlo);
    }
    __syncthreads();

    // ---- phase 8 (L4): rgb = sigmoid(h3 @ Wr + br)*1.002 - 0.001
    {
        int s = t >> 3, j = t & 7, k0 = j * 32;
        float p0 = 0.f, p1 = 0.f, p2 = 0.f;
        #pragma unroll 2
        for (int q = 0; q < 4; ++q) {
            us4 vh[2], vl[2];
            *reinterpret_cast<uint4*>(vh) = *reinterpret_cast<const uint4*>(&sXhi[s][k0 + q * 8]);
            *reinterpret_cast<uint4*>(vl) = *reinterpret_cast<const uint4*>(&sXlo[s][k0 + q * 8]);
            #pragma unroll
            for (int e = 0; e < 8; ++e) {
                int k = k0 + q * 8 + e;
                float hv = bf16f(((const unsigned short*)vh)[e]) + bf16f(((const unsigned short*)vl)[e]);
                p0 += hv * Wr[k * 3 + 0];
                p1 += hv * Wr[k * 3 + 1];
                p2 += hv * Wr[k * 3 + 2];
            }
        }
        #pragma unroll
        for (int m = 1; m < 8; m <<= 1) {
            p0 += __shfl_xor(p0, m);
            p1 += __shfl_xor(p1, m);
            p2 += __shfl_xor(p2, m);
        }
        if (j < 3) {
            float a = ((j == 0) ? p0 : (j == 1) ? p1 : p2) + br[j];
            float sg = 1.0f / (1.0f + expf(-a));
            outRGB[(size_t)(base + s) * 3 + j] = sg * 1.002f - 0.001f;
        }
    }
}

extern "C" void kernel_launch(void* const* d_in, const int* in_sizes, int n_in,
                              void* d_out, int out_size, void* d_ws, size_t ws_size,
                              hipStream_t stream) {
    const float* means = (const float*)d_in[1];
    const float* stds_ = (const float*)d_in[2];
    const float* vdirs = (const float*)d_in[3];
    const float* emb   = (const float*)d_in[4];
    const float* Wd0 = (const float*)d_in[5];
    const float* bd0 = (const float*)d_in[6];
    const float* Wd1 = (const float*)d_in[7];
    const float* bd1 = (const float*)d_in[8];
    const float* Wv0 = (const float*)d_in[9];
    const float* bv0 = (const float*)d_in[10];
    const float* Wv1 = (const float*)d_in[11];
    const float* bv1 = (const float*)d_in[12];
    const float* Wr  = (const float*)d_in[13];
    const float* br  = (const float*)d_in[14];

    const int B  = in_sizes[3] / 3;   // 1024 rays
    const int NS = B * 32;            // 32768 samples

    unsigned short* pk = (unsigned short*)d_ws;   // 424*1024 bf16 pairs = 868 KB

    hipLaunchKernelGGL(pack_weights_kernel, dim3((424 * 512 + 255) / 256), dim3(256), 0, stream,
                       Wd0, Wd1, Wv0, Wv1, pk);

    float* outD   = (float*)d_out;
    float* outRGB = outD + NS;
    hipLaunchKernelGGL(zip_fused_kernel, dim3(B), dim3(256), 0, stream,
                       means, stds_, vdirs, emb, pk,
                       bd0, bd1, Wv0, bv0, Wv1, bv1, Wr, br,
                       outD, outRGB);
}

// Round 9
// 189.300 us; speedup vs baseline: 1.2289x; 1.1433x over previous
//
#include <hip/hip_runtime.h>

#define HASH_T    2097152u
#define HASH_MASK 2097151u
#define PRIME1 2654435761u
#define PRIME2 805459861u

typedef __attribute__((ext_vector_type(8))) short bf16x8;
typedef __attribute__((ext_vector_type(4))) float f32x4;
typedef __attribute__((ext_vector_type(4))) unsigned short us4;

#define LDS_STRIDE 328   // cols 0..63 feat/act0, 64..319 x->h2->h3, pad 8

__device__ __forceinline__ unsigned short bf16_hi(float x){
    unsigned u = __float_as_uint(x);
    return (unsigned short)((u + 0x7FFFu + ((u >> 16) & 1u)) >> 16);
}
__device__ __forceinline__ float bf16f(unsigned short h){
    return __uint_as_float((unsigned)h << 16);
}
__device__ __forceinline__ void split2(float x, unsigned short& h, unsigned short& l){
    h = bf16_hi(x);
    l = bf16_hi(x - bf16f(h));
}

// ---------------- Kernel 0: pack weights into MFMA fragment order (bf16 hi/lo)
__global__ __launch_bounds__(256) void pack_weights_kernel(
    const float* __restrict__ Wd0, const float* __restrict__ Wd1,
    const float* __restrict__ Wv0, const float* __restrict__ Wv1,
    unsigned short* __restrict__ pk)
{
    int tid = blockIdx.x * 256 + threadIdx.x;
    if (tid >= 424 * 512) return;
    int pair = tid >> 9;
    int li   = tid & 511;
    int lane = li >> 3, j = li & 7;
    int kq = ((lane >> 4) << 3) + j;
    int cl = lane & 15;
    float w;
    if (pair < 8) {                       // Wd0 [40,64], K padded to 64
        int idx = pair; int kt = idx >> 2, ct = idx & 3;
        int k = kt * 32 + kq, c = ct * 16 + cl;
        w = (k < 40) ? Wd0[k * 64 + c] : 0.0f;
    } else if (pair < 40) {               // Wd1 [64,256]
        int idx = pair - 8; int kt = idx >> 4, ct = idx & 15;
        int k = kt * 32 + kq, c = ct * 16 + cl;
        w = Wd1[k * 256 + c];
    } else if (pair < 168) {              // Wv0 rows 0..255 (x part)
        int idx = pair - 40; int kt = idx >> 4, ct = idx & 15;
        int k = kt * 32 + kq, c = ct * 16 + cl;
        w = Wv0[k * 256 + c];
    } else {                              // Wv1: packed k 0..255 = ref rows 256..511 (x)
        int idx = pair - 168;             //      packed k 256..511 = ref rows 0..255 (h2)
        int kt = idx >> 4, ct = idx & 15;
        int k = kt * 32 + kq, c = ct * 16 + cl;
        int refr = (k < 256) ? (k + 256) : (k - 256);
        w = Wv1[refr * 256 + c];
    }
    unsigned short h, l; split2(w, h, l);
    pk[(size_t)pair * 1024 + li]       = h;
    pk[(size_t)pair * 1024 + 512 + li] = l;
}

// ---------------- fused kernel helpers --------------------------------------
template<int KT, int NC>
__device__ __forceinline__ void gemm32(
    const unsigned short* __restrict__ pkBase, int NCT, int ct0, int kOff,
    const unsigned short (*Ahi)[LDS_STRIDE], const unsigned short (*Alo)[LDS_STRIDE],
    int lane, f32x4 acc[NC][2])
{
    const int r = lane & 15;
    const int kg = (lane >> 4) * 8;
    bf16x8 ah[NC], al[NC];
    #pragma unroll
    for (int ci = 0; ci < NC; ++ci) {
        const unsigned short* pf = pkBase + (size_t)(ct0 + ci) * 1024 + (size_t)lane * 8;
        ah[ci] = *reinterpret_cast<const bf16x8*>(pf);
        al[ci] = *reinterpret_cast<const bf16x8*>(pf + 512);
    }
    #pragma unroll
    for (int kt = 0; kt < KT; ++kt) {
        bf16x8 ahn[NC], aln[NC];
        if (kt + 1 < KT) {
            #pragma unroll
            for (int ci = 0; ci < NC; ++ci) {
                const unsigned short* pf = pkBase
                    + (size_t)((kt + 1) * NCT + ct0 + ci) * 1024 + (size_t)lane * 8;
                ahn[ci] = *reinterpret_cast<const bf16x8*>(pf);
                aln[ci] = *reinterpret_cast<const bf16x8*>(pf + 512);
            }
        }
        const int ke = kOff + kt * 32 + kg;
        bf16x8 bh[2], bl[2];
        #pragma unroll
        for (int st = 0; st < 2; ++st) {
            bh[st] = *reinterpret_cast<const bf16x8*>(&Ahi[st * 16 + r][ke]);
            bl[st] = *reinterpret_cast<const bf16x8*>(&Alo[st * 16 + r][ke]);
        }
        #pragma unroll
        for (int ci = 0; ci < NC; ++ci) {
            #pragma unroll
            for (int st = 0; st < 2; ++st) {
                acc[ci][st] = __builtin_amdgcn_mfma_f32_16x16x32_bf16(ah[ci], bh[st], acc[ci][st], 0, 0, 0);
                acc[ci][st] = __builtin_amdgcn_mfma_f32_16x16x32_bf16(ah[ci], bl[st], acc[ci][st], 0, 0, 0);
                acc[ci][st] = __builtin_amdgcn_mfma_f32_16x16x32_bf16(al[ci], bh[st], acc[ci][st], 0, 0, 0);
            }
        }
        if (kt + 1 < KT) {
            #pragma unroll
            for (int ci = 0; ci < NC; ++ci) { ah[ci] = ahn[ci]; al[ci] = aln[ci]; }
        }
    }
}

template<int NC, bool RELU>
__device__ __forceinline__ void epi32(
    f32x4 acc[NC][2], int ct0, int lane, const float* bias, int outOff,
    unsigned short (*Ahi)[LDS_STRIDE], unsigned short (*Alo)[LDS_STRIDE])
{
    const int r = lane & 15, g = lane >> 4;
    #pragma unroll
    for (int ci = 0; ci < NC; ++ci) {
        const int c0 = (ct0 + ci) * 16 + g * 4;
        const float4 bb = *reinterpret_cast<const float4*>(&bias[c0]);
        #pragma unroll
        for (int st = 0; st < 2; ++st) {
            const int s = st * 16 + r;
            float v[4] = { acc[ci][st][0] + bb.x, acc[ci][st][1] + bb.y,
                           acc[ci][st][2] + bb.z, acc[ci][st][3] + bb.w };
            us4 H, L;
            #pragma unroll
            for (int q = 0; q < 4; ++q) {
                float vv = RELU ? fmaxf(v[q], 0.0f) : v[q];
                unsigned short h, l; split2(vv, h, l);
                H[q] = h; L[q] = l;
            }
            *reinterpret_cast<us4*>(&Ahi[s][outOff + c0]) = H;
            *reinterpret_cast<us4*>(&Alo[s][outOff + c0]) = L;
        }
    }
}

// hash helpers: per-level index/weight computation and consume+reduce+store
__device__ __forceinline__ void hash_level(
    float mx, float my, float mz, float sd2_8, float r,
    unsigned idx[8], float cw[8], float& wl)
{
    float px = (mx + 1.0f) * 0.5f * r - 0.5f;
    float py = (my + 1.0f) * 0.5f * r - 0.5f;
    float pz = (mz + 1.0f) * 0.5f * r - 0.5f;
    float fx = floorf(px), fy = floorf(py), fz = floorf(pz);
    float rx = px - fx, ry = py - fy, rz = pz - fz;
    int ix = (int)fx, iy = (int)fy, iz = (int)fz;
    unsigned hx[2] = { (unsigned)ix,          (unsigned)(ix + 1) };
    unsigned hy[2] = { (unsigned)iy * PRIME1, (unsigned)(iy + 1) * PRIME1 };
    unsigned hz[2] = { (unsigned)iz * PRIME2, (unsigned)(iz + 1) * PRIME2 };
    float wx[2] = { 1.0f - rx, rx };
    float wy[2] = { 1.0f - ry, ry };
    float wz[2] = { 1.0f - rz, rz };
    #pragma unroll
    for (int c = 0; c < 8; ++c) {
        int cx = (c >> 2) & 1, cy = (c >> 1) & 1, cz = c & 1;
        idx[c] = (hx[cx] ^ hy[cy] ^ hz[cz]) & HASH_MASK;
        cw[c] = wx[cx] * wy[cy] * wz[cz];
    }
    wl = erff(1.0f / fmaxf(sqrtf(sd2_8 * r * r), 1e-10f));
}

__device__ __forceinline__ void consume_level(
    const float4 e[8], const float cw[8], float wl, bool act,
    int n, int s, int l,
    unsigned short (*Ahi)[LDS_STRIDE], unsigned short (*Alo)[LDS_STRIDE])
{
    const float inv6 = 1.0f / 6.0f;
    float a0 = 0.f, a1 = 0.f, a2 = 0.f, a3 = 0.f;
    if (act) {
        #pragma unroll
        for (int c = 0; c < 8; ++c) {
            a0 += cw[c] * e[c].x; a1 += cw[c] * e[c].y;
            a2 += cw[c] * e[c].z; a3 += cw[c] * e[c].w;
        }
        a0 *= wl; a1 *= wl; a2 *= wl; a3 *= wl;
    }
    #pragma unroll
    for (int m = 1; m < 8; m <<= 1) {
        a0 += __shfl_xor(a0, m);
        a1 += __shfl_xor(a1, m);
        a2 += __shfl_xor(a2, m);
        a3 += __shfl_xor(a3, m);
    }
    if (n == 0) {
        float o[4] = { a0 * inv6, a1 * inv6, a2 * inv6, a3 * inv6 };
        us4 H, L;
        #pragma unroll
        for (int q = 0; q < 4; ++q) {
            unsigned short h, lo; split2(o[q], h, lo);
            H[q] = h; L[q] = lo;
        }
        *reinterpret_cast<us4*>(&Ahi[s][l * 4]) = H;
        *reinterpret_cast<us4*>(&Alo[s][l * 4]) = L;
    }
}

// ---------------- Kernel 1: fused hash-grid + MLP, one ray (32 samples)/block
__global__ __launch_bounds__(256, 3) void zip_fused_kernel(
    const float* __restrict__ means, const float* __restrict__ stds,
    const float* __restrict__ vdirs, const float* __restrict__ emb,
    const unsigned short* __restrict__ pk,
    const float* __restrict__ bd0, const float* __restrict__ bd1,
    const float* __restrict__ Wv0, const float* __restrict__ bv0,
    const float* __restrict__ Wv1, const float* __restrict__ bv1,
    const float* __restrict__ Wr,  const float* __restrict__ br,
    float* __restrict__ outD, float* __restrict__ outRGB)
{
    __shared__ __align__(16) unsigned short sAhi[32][LDS_STRIDE];
    __shared__ __align__(16) unsigned short sAlo[32][LDS_STRIDE];
    __shared__ float sDe[32];
    __shared__ float sDv0[256];
    __shared__ float sDv1[256];

    const int t = threadIdx.x;
    const int lane = t & 63;
    const int w = t >> 6;
    const int b = blockIdx.x;          // ray index
    const int base = b * 32;

    // ---- phase 0: zero-pad feat cols 40..63; dir encoding
    if (t < 192) {
        int s = t / 6, j = t - s * 6;
        us4 z = {0, 0, 0, 0};
        *reinterpret_cast<us4*>(&sAhi[s][40 + j * 4]) = z;
        *reinterpret_cast<us4*>(&sAlo[s][40 + j * 4]) = z;
    }
    if (t < 27) {
        float d0 = vdirs[b * 3 + 0], d1 = vdirs[b * 3 + 1], d2 = vdirs[b * 3 + 2];
        float val;
        if (t < 3) val = (t == 0) ? d0 : ((t == 1) ? d1 : d2);
        else {
            int u = t - 3, half = u / 12, jk = u % 12;
            int j = jk / 3, k = jk % 3;
            float dk = (k == 0) ? d0 : ((k == 1) ? d1 : d2);
            float xb = dk * (float)(1 << j);
            val = sinf(half ? (xb + 1.57079632679489662f) : xb);
        }
        sDe[t] = val;
    }
    __syncthreads();

    // ---- phase 1: hash gather, 2-level batched (16 outstanding loads/thread)
    {
        const int s = t >> 3, n = t & 7;
        const bool act = (n < 6);
        float mx = 0.f, my = 0.f, mz = 0.f, sd2_8 = 0.f;
        if (act) {
            const float* mp = means + ((size_t)(base + s) * 6 + n) * 3;
            mx = mp[0]; my = mp[1]; mz = mp[2];
            float sd = stds[(size_t)(base + s) * 6 + n];
            sd2_8 = 8.0f * sd * sd;
        }
        #pragma unroll 1
        for (int lp = 0; lp < 5; ++lp) {
            const int l0 = 2 * lp;
            const float r0 = (float)(16 << l0);
            const float r1 = r0 * 2.0f;
            const float* embL0 = emb + (size_t)l0 * HASH_T * 4u;
            const float* embL1 = embL0 + (size_t)HASH_T * 4u;
            unsigned idx0[8], idx1[8];
            float cw0[8], cw1[8];
            float wl0 = 0.f, wl1 = 0.f;
            if (act) {
                hash_level(mx, my, mz, sd2_8, r0, idx0, cw0, wl0);
                hash_level(mx, my, mz, sd2_8, r1, idx1, cw1, wl1);
            }
            float4 e0[8], e1[8];
            if (act) {
                #pragma unroll
                for (int c = 0; c < 8; ++c)
                    e0[c] = *reinterpret_cast<const float4*>(embL0 + (size_t)idx0[c] * 4u);
                #pragma unroll
                for (int c = 0; c < 8; ++c)
                    e1[c] = *reinterpret_cast<const float4*>(embL1 + (size_t)idx1[c] * 4u);
            }
            consume_level(e0, cw0, wl0, act, n, s, l0,     sAhi, sAlo);
            consume_level(e1, cw1, wl1, act, n, s, l0 + 1, sAhi, sAlo);
        }
    }
    __syncthreads();

    // ---- phase 2: per-ray dir-enc + bias tables (rank-27 correction)
    {
        int c = t;
        float a0 = bv0[c], a1 = bv1[c];
        #pragma unroll 3
        for (int k = 0; k < 27; ++k) {
            float dv = sDe[k];
            a0 += dv * Wv0[(256 + k) * 256 + c];
            a1 += dv * Wv1[(512 + k) * 256 + c];
        }
        sDv0[c] = a0; sDv1[c] = a1;
    }
    __syncthreads();

    // ---- phase 3 (L0): feat @ Wd0 -> act0 (cols 0..63), relu
    {
        f32x4 acc[1][2] = {};
        gemm32<2, 1>(pk, 4, w, 0, sAhi, sAlo, lane, acc);
        __syncthreads();                 // feat reads done before overwrite
        epi32<1, true>(acc, w, lane, bd0, 0, sAhi, sAlo);
    }
    __syncthreads();

    // ---- phase 4 (L1): act0 @ Wd1 -> x (cols 64..319); density from col 0
    {
        f32x4 acc[4][2] = {};
        gemm32<2, 4>(pk + 8192, 16, w * 4, 0, sAhi, sAlo, lane, acc);
        if (w == 0 && (lane >> 4) == 0) {
            #pragma unroll
            for (int st = 0; st < 2; ++st) {
                float x0 = acc[0][st][0] + bd1[0];
                int s = st * 16 + (lane & 15);
                float vv = x0 - 1.0f;
                outD[base + s] = fmaxf(vv, 0.0f) + log1pf(expf(-fabsf(vv)));
            }
        }
        __syncthreads();                 // act0 reads done
        epi32<4, false>(acc, w * 4, lane, bd1, 64, sAhi, sAlo);
    }
    __syncthreads();

    // ---- phase 5: px = x @ Wv1[x-rows] (L3 partial, registers only)
    f32x4 px[4][2] = {};
    gemm32<8, 4>(pk + 172032, 16, w * 4, 64, sAhi, sAlo, lane, px);
    __syncthreads();

    // ---- phase 6 (L2): x @ Wv0 + sDv0 -> h2 (cols 64..319, overwrites x)
    {
        f32x4 acc[4][2] = {};
        gemm32<8, 4>(pk + 40960, 16, w * 4, 64, sAhi, sAlo, lane, acc);
        __syncthreads();                 // all x reads (phase5+6) done
        epi32<4, true>(acc, w * 4, lane, sDv0, 64, sAhi, sAlo);
    }
    __syncthreads();

    // ---- phase 7 (L3): px + h2 @ Wv1[h2-rows] + sDv1 -> h3 (cols 64..319)
    {
        gemm32<8, 4>(pk + 303104, 16, w * 4, 64, sAhi, sAlo, lane, px);
        __syncthreads();                 // h2 reads done before overwrite
        epi32<4, true>(px, w * 4, lane, sDv1, 64, sAhi, sAlo);
    }
    __syncthreads();

    // ---- phase 8 (L4): rgb = sigmoid(h3 @ Wr + br)*1.002 - 0.001
    {
        int s = t >> 3, j = t & 7, k0 = 64 + j * 32;
        float p0 = 0.f, p1 = 0.f, p2 = 0.f;
        #pragma unroll 2
        for (int q = 0; q < 4; ++q) {
            us4 vh[2], vl[2];
            *reinterpret_cast<uint4*>(vh) = *reinterpret_cast<const uint4*>(&sAhi[s][k0 + q * 8]);
            *reinterpret_cast<uint4*>(vl) = *reinterpret_cast<const uint4*>(&sAlo[s][k0 + q * 8]);
            #pragma unroll
            for (int e = 0; e < 8; ++e) {
                int k = j * 32 + q * 8 + e;
                float hv = bf16f(((const unsigned short*)vh)[e]) + bf16f(((const unsigned short*)vl)[e]);
                p0 += hv * Wr[k * 3 + 0];
                p1 += hv * Wr[k * 3 + 1];
                p2 += hv * Wr[k * 3 + 2];
            }
        }
        #pragma unroll
        for (int m = 1; m < 8; m <<= 1) {
            p0 += __shfl_xor(p0, m);
            p1 += __shfl_xor(p1, m);
            p2 += __shfl_xor(p2, m);
        }
        if (j < 3) {
            float a = ((j == 0) ? p0 : (j == 1) ? p1 : p2) + br[j];
            float sg = 1.0f / (1.0f + expf(-a));
            outRGB[(size_t)(base + s) * 3 + j] = sg * 1.002f - 0.001f;
        }
    }
}

extern "C" void kernel_launch(void* const* d_in, const int* in_sizes, int n_in,
                              void* d_out, int out_size, void* d_ws, size_t ws_size,
                              hipStream_t stream) {
    const float* means = (const float*)d_in[1];
    const float* stds_ = (const float*)d_in[2];
    const float* vdirs = (const float*)d_in[3];
    const float* emb   = (const float*)d_in[4];
    const float* Wd0 = (const float*)d_in[5];
    const float* bd0 = (const float*)d_in[6];
    const float* Wd1 = (const float*)d_in[7];
    const float* bd1 = (const float*)d_in[8];
    const float* Wv0 = (const float*)d_in[9];
    const float* bv0 = (const float*)d_in[10];
    const float* Wv1 = (const float*)d_in[11];
    const float* bv1 = (const float*)d_in[12];
    const float* Wr  = (const float*)d_in[13];
    const float* br  = (const float*)d_in[14];

    const int B  = in_sizes[3] / 3;   // 1024 rays
    const int NS = B * 32;            // 32768 samples

    unsigned short* pk = (unsigned short*)d_ws;   // 424*1024 bf16 pairs = 868 KB

    hipLaunchKernelGGL(pack_weights_kernel, dim3((424 * 512 + 255) / 256), dim3(256), 0, stream,
                       Wd0, Wd1, Wv0, Wv1, pk);

    float* outD   = (float*)d_out;
    float* outRGB = outD + NS;
    hipLaunchKernelGGL(zip_fused_kernel, dim3(B), dim3(256), 0, stream,
                       means, stds_, vdirs, emb, pk,
                       bd0, bd1, Wv0, bv0, Wv1, bv1, Wr, br,
                       outD, outRGB);
}